// Round 12
// baseline (421.948 us; speedup 1.0000x reference)
//
#include <hip/hip_runtime.h>
#include <hip/hip_bf16.h>

#define D_IN 512
#define NEXP 32
#define HID 16
#define NT 34            // 544 cols / 16
#define KSTEPS 16        // 512 / 32
#define BM 128           // rows per block
#define BATCH 262144
#define GXLA 129         // padded row stride for gate LDS
#define SPW 5            // B-stage ops per wave (8 waves x 5 = 40 >= 34, 6 dups)

typedef __attribute__((ext_vector_type(8))) short bfrag;   // 8 x bf16
typedef __attribute__((ext_vector_type(4))) float f32x4;

__device__ inline ushort f2bf(float f) {
  uint32_t u = __float_as_uint(f);
  u += 0x7fffu + ((u >> 16) & 1u);      // RNE, finite inputs
  return (ushort)(u >> 16);
}

// pack 8 fp32 -> 8 bf16 (RNE) with v_cvt_pk_bf16_f32
__device__ inline bfrag cvt8(const float4 a, const float4 b) {
  union { bfrag v; uint u[4]; } r;
  asm("v_cvt_pk_bf16_f32 %0, %1, %2" : "=v"(r.u[0]) : "v"(a.x), "v"(a.y));
  asm("v_cvt_pk_bf16_f32 %0, %1, %2" : "=v"(r.u[1]) : "v"(a.z), "v"(a.w));
  asm("v_cvt_pk_bf16_f32 %0, %1, %2" : "=v"(r.u[2]) : "v"(b.x), "v"(b.y));
  asm("v_cvt_pk_bf16_f32 %0, %1, %2" : "=v"(r.u[3]) : "v"(b.z), "v"(b.w));
  return r.v;
}

// tanh-form GELU, exp-based
__device__ inline float gelu_t(float v) {
  float t = 0.7978845608028654f * fmaf(0.044715f * v * v, v, v);
  t = fminf(fmaxf(t, -9.f), 9.f);
  float e = __expf(-2.f * t);
  float th = (1.f - e) * __builtin_amdgcn_rcpf(1.f + e);
  return 0.5f * v * (1.f + th);
}

__device__ inline void gload_lds16(const ushort* g, ushort* l) {
  __builtin_amdgcn_global_load_lds(
      (const __attribute__((address_space(1))) void*)g,
      (__attribute__((address_space(3))) void*)l, 16, 0, 0);
}

// ---- Pre-pack Wcat[512,544] into bf16 MFMA fragment order:
// P[ks][t][lane][j] = Wcat[k=ks*32+(l>>4)*8+j][n=t*16+(l&15)]
__global__ void prepack_kernel(const float* __restrict__ Wg,
                               const float* __restrict__ W1,
                               ushort* __restrict__ P) {
  int tid = blockIdx.x * 256 + threadIdx.x;
  const int total = KSTEPS * NT * 64;
  if (tid >= total) return;
  int l  = tid & 63;
  int t  = (tid >> 6) % NT;
  int ks = tid / (NT * 64);
  int n  = t * 16 + (l & 15);
  int kb = ks * 32 + (l >> 4) * 8;
  __align__(16) ushort v[8];
#pragma unroll
  for (int j = 0; j < 8; ++j) {
    int k = kb + j;
    float w;
    if (n < NEXP) {
      w = Wg[n * D_IN + k];
    } else {
      int e = (n - 32) >> 4, h = (n - 32) & 15;
      w = W1[(e * D_IN + k) * HID + h];
    }
    v[j] = f2bf(w);
  }
  *reinterpret_cast<int4*>(P + (size_t)tid * 8) = *reinterpret_cast<const int4*>(v);
}

// ---- Main fused kernel: 512 thr = 8 waves (R11's validated block shape and
// fence skeleton), BM=128. NEW decomposition: wm = wid&1 (64-row half),
// wn = wid>>1 (tile quarter: tiles 0-8/9-17/18-25/26-33). Wave tile = 64 rows
// x 9 tiles -> acc[4][9] (144 regs); per-wave per-kstep 9 ds_read_b128 feed 36
// MFMAs (B-reuse 4 vs round-11's 2 -> halves LDS read traffic). B triple-
// buffered via global_load_lds (SPW=5/wave, R11 verbatim); A global->reg,
// 1-kstep prefetch (8 float4). Fences: vmcnt(13) = A(8)+Bnext(5) in flight;
// tail vmcnt(8). Epilogue = R5/R6's validated gall pattern.
// acc = mfma(Wfrag, xfrag) -> C^T: lane&15 = batch row (in its 16-group),
// (l>>4)*4+r = col-in-tile.
__global__ __launch_bounds__(512, 2)
void moe_kernel(const float* __restrict__ x, const ushort* __restrict__ P,
                const float* __restrict__ b1, const float* __restrict__ W2,
                const float* __restrict__ b2, float* __restrict__ out) {
  __shared__ __align__(16) ushort Blds[3][NT * 512];   // 104448 B
  __shared__ float gall[NEXP * GXLA];  // 16512 B: all 32 gate-exps per row
  __shared__ float pp[4][BM];          // 2048 B: per-wn partials
  __shared__ float sl[BM];             // 512 B: softmax denom

  const int tid = threadIdx.x;
  const int l = tid & 63;
  const int wid = tid >> 6;
  const int wm = wid & 1;              // 64-row half
  const int wn = wid >> 1;             // tile quarter 0..3
  const int lane16 = l & 15, lg = l >> 4;
  const size_t rowBase = (size_t)blockIdx.x * BM;
  const int tbase = wn * 9 - (wn == 3);     // 0, 9, 18, 26
  const int ntile = (wn < 2) ? 9 : 8;       // 9/9/8/8, no dups

  // this wave's 5 staging tiles (wave-uniform, static-indexed) — R11 verbatim
  int stg[SPW];
#pragma unroll
  for (int i = 0; i < SPW; ++i) {
    int t = wid * SPW + i;
    stg[i] = (t >= NT) ? (t - NT) : t;
  }

  f32x4 acc[4][9];
#pragma unroll
  for (int f = 0; f < 4; ++f)
#pragma unroll
    for (int i = 0; i < 9; ++i) acc[f][i] = (f32x4){0.f, 0.f, 0.f, 0.f};

  // x fragment f: row = rowBase + wm*64 + f*16 + lane16, k = ks*32 + lg*8 + j
  const float* xr = x + (rowBase + wm * 64 + lane16) * D_IN + lg * 8;

  float4 abuf[8];

  // ---- prologue: issue A(0), then B(0) and B(1); drain A(0)+B(0), keep B(1)
#pragma unroll
  for (int f = 0; f < 4; ++f) {
    abuf[f * 2]     = *reinterpret_cast<const float4*>(xr + f * 16 * D_IN);
    abuf[f * 2 + 1] = *reinterpret_cast<const float4*>(xr + f * 16 * D_IN + 4);
  }
#pragma unroll
  for (int g = 0; g < 2; ++g)
#pragma unroll
    for (int i = 0; i < SPW; ++i)
      gload_lds16(P + ((size_t)(g * NT + stg[i]) * 64 + l) * 8,
                  &Blds[g][stg[i] * 512]);
  asm volatile("s_waitcnt vmcnt(5)" ::: "memory");   // A(0)+B(0) done; B(1) flying
  __builtin_amdgcn_s_barrier();

#pragma unroll
  for (int ks = 0; ks < KSTEPS; ++ks) {
    const int rb = ks % 3;
    // consume A(ks): compiler inserts the precise vmcnt wait for abuf
    bfrag a[4];
#pragma unroll
    for (int f = 0; f < 4; ++f) a[f] = cvt8(abuf[f * 2], abuf[f * 2 + 1]);
    if (ks < KSTEPS - 1) {
      // issue A(ks+1) (reuses abuf regs — WAR resolved by the cvt above)
#pragma unroll
      for (int f = 0; f < 4; ++f) {
        abuf[f * 2]     = *reinterpret_cast<const float4*>(xr + f * 16 * D_IN + (ks + 1) * 32);
        abuf[f * 2 + 1] = *reinterpret_cast<const float4*>(xr + f * 16 * D_IN + (ks + 1) * 32 + 4);
      }
    }
    if (ks < KSTEPS - 2) {
      // issue B(ks+2) into buf[(ks+2)%3] (~2 ksteps of slack)
      const int wb = (ks + 2) % 3;
#pragma unroll
      for (int i = 0; i < SPW; ++i)
        gload_lds16(P + ((size_t)((ks + 2) * NT + stg[i]) * 64 + l) * 8,
                    &Blds[wb][stg[i] * 512]);
    }
#pragma unroll
    for (int i = 0; i < 9; ++i) {
      if (i < ntile) {
        const bfrag b = *reinterpret_cast<const bfrag*>(
            &Blds[rb][(tbase + i) * 512 + (l << 3)]);
#pragma unroll
        for (int f = 0; f < 4; ++f)
          acc[f][i] = __builtin_amdgcn_mfma_f32_16x16x32_bf16(b, a[f], acc[f][i], 0, 0, 0);
      }
    }
    if (ks < KSTEPS - 1) {
      if (ks < KSTEPS - 2)
        asm volatile("s_waitcnt vmcnt(13)" ::: "memory"); // drain B(ks+1); keep A(8)+B(ks+2)(5)
      else
        asm volatile("s_waitcnt vmcnt(8)" ::: "memory");  // drain B(K-1); keep A(8)
      __builtin_amdgcn_s_barrier();
    }
  }

  // ---- epilogue (R5/R6 validated pattern). C^T: lane16 = row-in-16-group,
  // lg*4+r = col-in-tile. Rows of this wave: wm*64 + f*16 + lane16, f=0..3.
  const int row0 = wm * 64 + lane16;

  if (wn == 0) {
    // gating softmax from tiles 0,1: expert e = i*16 + lg*4 + r
#pragma unroll
    for (int f = 0; f < 4; ++f) {
      const int row = row0 + f * 16;
      float mx = fmaxf(fmaxf(fmaxf(acc[f][0][0], acc[f][0][1]), fmaxf(acc[f][0][2], acc[f][0][3])),
                       fmaxf(fmaxf(acc[f][1][0], acc[f][1][1]), fmaxf(acc[f][1][2], acc[f][1][3])));
      mx = fmaxf(mx, __shfl_xor(mx, 16));
      mx = fmaxf(mx, __shfl_xor(mx, 32));
      float sum = 0.f;
#pragma unroll
      for (int t = 0; t < 2; ++t)
#pragma unroll
        for (int r = 0; r < 4; ++r) {
          float g = __expf(acc[f][t][r] - mx);
          sum += g;
          gall[(t * 16 + lg * 4 + r) * GXLA + row] = g;
        }
      sum += __shfl_xor(sum, 16);
      sum += __shfl_xor(sum, 32);
      if (lg == 0) sl[row] = sum;
    }
  }
  __syncthreads();   // gates + denom visible to all waves

  // experts: tile t = tbase+i holds expert e = t-2, valid for t >= 2
  // coverage: wn0 e0-6 (i>=2), wn1 e7-15, wn2 e16-23, wn3 e24-31 (7+9+8+8=32)
  float pacc[4] = {0.f, 0.f, 0.f, 0.f};
#pragma unroll
  for (int i = 0; i < 9; ++i) {
    const bool valid = (i < ntile) && ((wn != 0) || (i >= 2));
    if (valid) {
      const int e = tbase + i - 2;
      const float4 b1v = *reinterpret_cast<const float4*>(b1 + e * HID + lg * 4);
      const float4 w2v = *reinterpret_cast<const float4*>(W2 + e * HID + lg * 4);
      const float b2v = b2[e];
#pragma unroll
      for (int f = 0; f < 4; ++f) {
        float p = gelu_t(acc[f][i][0] + b1v.x) * w2v.x;
        p = fmaf(gelu_t(acc[f][i][1] + b1v.y), w2v.y, p);
        p = fmaf(gelu_t(acc[f][i][2] + b1v.z), w2v.z, p);
        p = fmaf(gelu_t(acc[f][i][3] + b1v.w), w2v.w, p);
        p += __shfl_xor(p, 16);
        p += __shfl_xor(p, 32);             // o_e valid in all lanes
        pacc[f] = fmaf(p + b2v, gall[e * GXLA + row0 + f * 16], pacc[f]);
      }
    }
  }
  if (lg == 0) {
#pragma unroll
    for (int f = 0; f < 4; ++f) pp[wn][row0 + f * 16] = pacc[f];
  }
  __syncthreads();
  if (tid < BM) {
    float a = pp[0][tid] + pp[1][tid] + pp[2][tid] + pp[3][tid];
    out[rowBase + tid] = a / sl[tid];
  }
}

extern "C" void kernel_launch(void* const* d_in, const int* in_sizes, int n_in,
                              void* d_out, int out_size, void* d_ws, size_t ws_size,
                              hipStream_t stream) {
  const float* x  = (const float*)d_in[0];
  const float* Wg = (const float*)d_in[1];
  const float* W1 = (const float*)d_in[2];
  const float* b1 = (const float*)d_in[3];
  const float* W2 = (const float*)d_in[4];
  const float* b2 = (const float*)d_in[5];
  float* out = (float*)d_out;
  ushort* P = (ushort*)d_ws;   // 16*34*64*8*2 = 557,056 B

  hipLaunchKernelGGL(prepack_kernel, dim3((KSTEPS * NT * 64 + 255) / 256), dim3(256),
                     0, stream, Wg, W1, P);
  hipLaunchKernelGGL(moe_kernel, dim3(BATCH / BM), dim3(512),
                     0, stream, x, P, b1, W2, b2, out);
}